// Round 11
// baseline (1840.313 us; speedup 1.0000x reference)
//
#include <hip/hip_runtime.h>

#define HID 256
#define T_STEPS 1024
#define F_IN 40
#define NSPK 1251
#define NCHUNK 8            // workgroups per layer
#define NBLOCKS 64          // 8 XCD slots x 8 chunks; blocks with (bid&7)>=3 exit
#define K2_THREADS 512

// workspace layout:
//   tagged h words: u64 hbuf[3][1025][256]       (shared path: prev-layer consumers)
//   mailboxes:      u64 mbox[3][8][8][256]       [layer][consumer][slot=t%8][k]
//     private per-consumer copies of the same tagged words -> each polled line is
//     read by exactly ONE wave of ONE block (kills same-line poll queueing)
//   plain float h2f[1024][256] for the logits GEMM
#define HBUF_WORDS (3 * 1025 * 256)
#define MBOX_SLOTS 8
#define MBOX_WORDS (3 * 8 * MBOX_SLOTS * 256)
#define H2F_OFF_BYTES ((size_t)(HBUF_WORDS + MBOX_WORDS) * 8)

__device__ __forceinline__ float fast_sig(float v) {
    return __builtin_amdgcn_rcpf(1.f + __expf(-v));
}
__device__ __forceinline__ float fast_tanh(float v) {
    return 2.f * __builtin_amdgcn_rcpf(1.f + __expf(-2.f * v)) - 1.f;
}

// Agent-scope pipelined tagged-word poll. Depth 4 (R10: depth 6 regressed -- extra
// same-address samples queue at the coherence point; 4 is the measured optimum).
// Word is write-once per tag epoch so any matching sample is valid.
__device__ __forceinline__ float poll_word(const unsigned long long* p, unsigned want) {
    unsigned long long v0 = __hip_atomic_load(p, __ATOMIC_RELAXED, __HIP_MEMORY_SCOPE_AGENT);
    if ((unsigned)(v0 >> 32) == want) return __uint_as_float((unsigned)v0);  // steady-state hit
    unsigned long long v1 = __hip_atomic_load(p, __ATOMIC_RELAXED, __HIP_MEMORY_SCOPE_AGENT);
    unsigned long long v2 = __hip_atomic_load(p, __ATOMIC_RELAXED, __HIP_MEMORY_SCOPE_AGENT);
    unsigned long long v3 = __hip_atomic_load(p, __ATOMIC_RELAXED, __HIP_MEMORY_SCOPE_AGENT);
    for (;;) {
        if ((unsigned)(v0 >> 32) == want) return __uint_as_float((unsigned)v0);
        v0 = v1; v1 = v2; v2 = v3;
        v3 = __hip_atomic_load(p, __ATOMIC_RELAXED, __HIP_MEMORY_SCOPE_AGENT);
    }
}

// ---------------- K0: init hbuf t=0 rows + all mailbox slots ----------------
__global__ void k0_init(unsigned long long* __restrict__ hbuf) {
    int tid = threadIdx.x;
    if (tid < 3 * HID) {
        int l = tid / HID, k = tid % HID;
        hbuf[(size_t)(l * 1025 + 0) * HID + k] = 0ull;   // tag 0, value 0.0f
    }
    // zero all mailbox words: slot 0 (tag 0, h=0) serves the t=0 read; slots 1..7
    // hold tag 0 which never false-matches (expected tags are strictly increasing)
    unsigned long long* mbox = hbuf + HBUF_WORDS;
    for (int i = tid; i < MBOX_WORDS; i += 1024) mbox[i] = 0ull;
}

// ---------------- K2: pipelined 3-layer LSTM, tagged-word sync ----------------
// R4 structure (best measured: k2 1540us) + per-consumer mailboxes on the
// critical same-layer path. Block mapping: bid = g*8 + layer (XCD co-location,
// cuts HBM/MALL traffic -- R3).
// Thread mapping (block = one layer-chunk of 32 h):
//   seg = tid >> 5 (0..15): 32-wide k-segment of [input(256); own-h(256)]
//   wave w owns segs {2w,2w+1} -- gather/bounce/dot are wave-private.
// Per step per wave: poll 1 word/lane -> ds_write_b32 -> 8x broadcast ds_read_b128
// + 128 FMA (R=4) -> shfl_xor(32) seg-fold -> one packed ds_write_b128 into parity
// gatebuf -> ONE s_barrier -> wave 0 sums 8 partials, nonlinearity, publish:
//   (a) 8 private mailbox copies (critical same-layer consumers, FIRST)
//   (b) shared hbuf word (slack-tolerant next-layer consumer + h2f for layer 2)
__global__ __launch_bounds__(K2_THREADS) void k2_lstm(
    const float* __restrict__ x,
    const float* __restrict__ w_ih0, const float* __restrict__ w_hh0,
    const float* __restrict__ b_ih0, const float* __restrict__ b_hh0,
    const float* __restrict__ w_ih1, const float* __restrict__ w_hh1,
    const float* __restrict__ b_ih1, const float* __restrict__ b_hh1,
    const float* __restrict__ w_ih2, const float* __restrict__ w_hh2,
    const float* __restrict__ b_ih2, const float* __restrict__ b_hh2,
    unsigned long long* __restrict__ hbuf, float* __restrict__ h2f)
{
    const int bid = blockIdx.x;
    const int xslot = bid & 7;           // XCD slot under round-robin dispatch
    if (xslot >= 3) return;              // only 3 layers; 40 of 64 blocks idle-exit
    const int layer = xslot;             // all 8 chunks of a layer share an XCD
    const int g     = bid >> 3;          // chunk of 32 h-indices
    const int tid   = threadIdx.x;
    const int seg = tid >> 5;            // k-segment 0..15 (32 wide each)
    const int j   = tid & 31;            // local h-index
    const int wv  = tid >> 6;            // wave 0..7
    const int jg  = g * 32 + j;          // global h-index within layer

    const float* wih = (layer == 0) ? w_ih0 : (layer == 1) ? w_ih1 : w_ih2;
    const float* whh = (layer == 0) ? w_hh0 : (layer == 1) ? w_hh1 : w_hh2;
    const float* bih = (layer == 0) ? b_ih0 : (layer == 1) ? b_ih1 : b_ih2;
    const float* bhh = (layer == 0) ? b_hh0 : (layer == 1) ? b_hh1 : b_hh2;

    // layer 0: k in [64,256) is all-zero input -> waves 1..3 have nothing to do
    const bool dead = (layer == 0) && (seg >= 2) && (seg < 8);

    __shared__ float  buf[512];          // bounce buffer; wave-private 64-word regions
    __shared__ float4 gatebuf[2][8][32]; // [t-parity][wave][j] = 4 gate partials

    // ---- weights: w[q][i] = W_row(q*256+jg)[ seg*32 + i ]  (contiguous) ----
    float w[4][32];
    float bb[4];
    if (!dead) {
        #pragma unroll
        for (int q = 0; q < 4; q++) {
            const int r = q * 256 + jg;
            bb[q] = bih[r] + bhh[r];
            const int k0 = seg * 32;
            if (k0 >= 256) {
                const float4* src = (const float4*)(whh + (size_t)r * HID + (k0 - 256));
                #pragma unroll
                for (int i4 = 0; i4 < 8; i4++) {
                    float4 v = src[i4];
                    w[q][i4*4+0] = v.x; w[q][i4*4+1] = v.y;
                    w[q][i4*4+2] = v.z; w[q][i4*4+3] = v.w;
                }
            } else if (layer > 0) {
                const float4* src = (const float4*)(wih + (size_t)r * HID + k0);
                #pragma unroll
                for (int i4 = 0; i4 < 8; i4++) {
                    float4 v = src[i4];
                    w[q][i4*4+0] = v.x; w[q][i4*4+1] = v.y;
                    w[q][i4*4+2] = v.z; w[q][i4*4+3] = v.w;
                }
            } else {
                // layer 0, seg 0/1: 40-wide x projection, zero-padded
                #pragma unroll
                for (int i = 0; i < 32; i++) {
                    int k = k0 + i;
                    w[q][i] = (k < F_IN) ? w_ih0[r * F_IN + k] : 0.f;
                }
            }
        }
    } else {
        #pragma unroll
        for (int q = 0; q < 4; q++) {
            bb[q] = 0.f;
            #pragma unroll
            for (int i = 0; i < 32; i++) w[q][i] = 0.f;
        }
    }

    for (int i = tid; i < 512; i += K2_THREADS) buf[i] = 0.f;
    __syncthreads();

    const float* x63 = x + 63 * T_STEPS * F_IN;
    const unsigned long long* h_prev = hbuf + (size_t)(layer - 1) * 1025 * HID; // layer>0 only
    unsigned long long* h_own        = hbuf + (size_t)layer * 1025 * HID;
    unsigned long long* mbox         = hbuf + HBUF_WORDS;
    // this block's private inbox: mbox[layer][g][slot][k]
    unsigned long long* my_inbox     = mbox + ((size_t)(layer * 8 + g) * MBOX_SLOTS) * 256;

    float px = 0.f;                      // layer-0 x prefetch (lanes tid<40)
    if (layer == 0 && tid < F_IN) px = x63[tid];

    float c_state = 0.f;                 // valid on tid<32 (update lanes, wave 0)

    for (int t = 0; t < T_STEPS; t++) {
        // ---- gather: each lane polls/loads word tid of the 512-wide input vec ----
        if (!dead) {
            if (tid < 256) {
                if (layer > 0) {
                    // prev-layer h[t+1] via SHARED hbuf (one period of slack)
                    buf[tid] = poll_word(h_prev + (size_t)(t + 1) * HID + tid,
                                         (unsigned)(t + 1));
                } else if (tid < F_IN) {
                    buf[tid] = px;       // prefetched x[t]; issue load of x[t+1]
                    if (t + 1 < T_STEPS) px = x63[(t + 1) * F_IN + tid];
                }
                // layer 0, 40 <= tid < 256: stays 0 (weights there are 0 too)
            } else {
                // own-layer h[t] via PRIVATE mailbox -- each polled line is read by
                // exactly one wave on the whole device (no same-line queueing)
                buf[tid] = poll_word(my_inbox + (size_t)(t & (MBOX_SLOTS - 1)) * 256
                                              + (tid - 256),
                                     (unsigned)t);
            }
        }

        // ---- wave-private bounce: ds_write above, broadcast ds_read_b128 below ----
        float4 part = make_float4(0.f, 0.f, 0.f, 0.f);
        if (!dead) {
            __asm__ volatile("s_waitcnt lgkmcnt(0)" ::: "memory");
            const float4* b4 = (const float4*)buf + seg * 8;
            float a0 = 0.f, a1 = 0.f, a2 = 0.f, a3 = 0.f;
            #pragma unroll
            for (int i4 = 0; i4 < 8; i4++) {
                float4 f = b4[i4];
                a0 += w[0][i4*4+0]*f.x + w[0][i4*4+1]*f.y + w[0][i4*4+2]*f.z + w[0][i4*4+3]*f.w;
                a1 += w[1][i4*4+0]*f.x + w[1][i4*4+1]*f.y + w[1][i4*4+2]*f.z + w[1][i4*4+3]*f.w;
                a2 += w[2][i4*4+0]*f.x + w[2][i4*4+1]*f.y + w[2][i4*4+2]*f.z + w[2][i4*4+3]*f.w;
                a3 += w[3][i4*4+0]*f.x + w[3][i4*4+1]*f.y + w[3][i4*4+2]*f.z + w[3][i4*4+3]*f.w;
            }
            // fold the wave's two segs (lanes L and L^32 share j)
            a0 += __shfl_xor(a0, 32, 64);
            a1 += __shfl_xor(a1, 32, 64);
            a2 += __shfl_xor(a2, 32, 64);
            a3 += __shfl_xor(a3, 32, 64);
            part = make_float4(a0, a1, a2, a3);
        }
        // one packed b128 write per wave (lanes 0..31): full-rate, conflict-free
        if ((tid & 32) == 0) gatebuf[t & 1][wv][j] = part;
        __syncthreads();                 // the ONLY barrier per step

        // ---- update + publish (wave 0, lanes 0..31) ----
        if (tid < 32) {
            float4 s = gatebuf[t & 1][0][tid];
            #pragma unroll
            for (int w8 = 1; w8 < 8; w8++) {
                float4 v = gatebuf[t & 1][w8][tid];
                s.x += v.x; s.y += v.y; s.z += v.z; s.w += v.w;
            }
            float si = fast_sig(s.x + bb[0]);
            float sf = fast_sig(s.y + bb[1]);
            float gg = fast_tanh(s.z + bb[2]);
            float so = fast_sig(s.w + bb[3]);
            c_state = sf * c_state + si * gg;
            float hv = so * fast_tanh(c_state);
            unsigned long long word =
                ((unsigned long long)(unsigned)(t + 1) << 32) | (unsigned long long)__float_as_uint(hv);

            // (a) 8 private mailbox copies FIRST -- the critical-cycle consumers
            const size_t slot_off = (size_t)((t + 1) & (MBOX_SLOTS - 1)) * 256 + g * 32 + tid;
            #pragma unroll
            for (int c = 0; c < 8; c++) {
                __hip_atomic_store(mbox + ((size_t)(layer * 8 + c) * MBOX_SLOTS) * 256 + slot_off,
                                   word, __ATOMIC_RELAXED, __HIP_MEMORY_SCOPE_AGENT);
            }
            // (b) shared hbuf word -- next-layer consumer (has a period of slack)
            __hip_atomic_store(h_own + (size_t)(t + 1) * HID + g * 32 + tid, word,
                               __ATOMIC_RELAXED, __HIP_MEMORY_SCOPE_AGENT);
            if (layer == 2) h2f[(size_t)t * HID + g * 32 + tid] = hv;
        }
        // gatebuf WAR across steps is safe: writers of parity p at step t+2 have
        // passed barrier(t+1), which wave 0 reaches only after reading parity p at
        // step t. Mailbox ring reuse is safe: tags strictly increase, 8 slots deep.
    }
}

// ---------------- K3: logits = h2 @ w_lin^T + b_lin (tiled fp32 GEMM) ----------------
#define BM 64
#define BN 64
#define BK 32
__global__ __launch_bounds__(256) void k3_logits(
    const float* __restrict__ A, const float* __restrict__ w_lin,
    const float* __restrict__ b_lin, float* __restrict__ out)
{
    int m0 = blockIdx.x * BM;
    int n0 = blockIdx.y * BN;
    int tid = threadIdx.x;
    __shared__ float As[BM][BK + 1];
    __shared__ float Bs[BN][BK + 1];
    float accv[4][4] = {};
    int tx = tid % 16, ty = tid / 16;

    for (int k0 = 0; k0 < HID; k0 += BK) {
        int row = tid / 4;
        int kq  = (tid % 4) * 8;
        {
            const float4* src = (const float4*)(A + (m0 + row) * HID + k0 + kq);
            float4 v0 = src[0], v1 = src[1];
            As[row][kq + 0] = v0.x; As[row][kq + 1] = v0.y; As[row][kq + 2] = v0.z; As[row][kq + 3] = v0.w;
            As[row][kq + 4] = v1.x; As[row][kq + 5] = v1.y; As[row][kq + 6] = v1.z; As[row][kq + 7] = v1.w;
        }
        {
            int n = n0 + row;
            float4 v0 = make_float4(0.f, 0.f, 0.f, 0.f), v1 = v0;
            if (n < NSPK) {
                const float4* src = (const float4*)(w_lin + n * HID + k0 + kq);
                v0 = src[0]; v1 = src[1];
            }
            Bs[row][kq + 0] = v0.x; Bs[row][kq + 1] = v0.y; Bs[row][kq + 2] = v0.z; Bs[row][kq + 3] = v0.w;
            Bs[row][kq + 4] = v1.x; Bs[row][kq + 5] = v1.y; Bs[row][kq + 6] = v1.z; Bs[row][kq + 7] = v1.w;
        }
        __syncthreads();
        #pragma unroll
        for (int kk = 0; kk < BK; kk++) {
            float a0 = As[ty * 4 + 0][kk], a1 = As[ty * 4 + 1][kk];
            float a2 = As[ty * 4 + 2][kk], a3 = As[ty * 4 + 3][kk];
            float b0 = Bs[tx * 4 + 0][kk], b1 = Bs[tx * 4 + 1][kk];
            float b2 = Bs[tx * 4 + 2][kk], b3 = Bs[tx * 4 + 3][kk];
            accv[0][0] += a0 * b0; accv[0][1] += a0 * b1; accv[0][2] += a0 * b2; accv[0][3] += a0 * b3;
            accv[1][0] += a1 * b0; accv[1][1] += a1 * b1; accv[1][2] += a1 * b2; accv[1][3] += a1 * b3;
            accv[2][0] += a2 * b0; accv[2][1] += a2 * b1; accv[2][2] += a2 * b2; accv[2][3] += a2 * b3;
            accv[3][0] += a3 * b0; accv[3][1] += a3 * b1; accv[3][2] += a3 * b2; accv[3][3] += a3 * b3;
        }
        __syncthreads();
    }
    #pragma unroll
    for (int i = 0; i < 4; i++) {
        int m = m0 + ty * 4 + i;
        #pragma unroll
        for (int j = 0; j < 4; j++) {
            int n = n0 + tx * 4 + j;
            if (n < NSPK) out[(size_t)m * NSPK + n] = accv[i][j] + b_lin[n];
        }
    }
}

// ---------------- K4: in-place row-wise log_softmax over NSPK ----------------
__global__ __launch_bounds__(256) void k4_logsoftmax(float* __restrict__ out)
{
    int t = blockIdx.x;
    float* row = out + (size_t)t * NSPK;
    int tid = threadIdx.x;
    __shared__ float red[8];
    float vals[5];
    float lmax = -1e30f;
    #pragma unroll
    for (int k = 0; k < 5; k++) {
        int n = tid + k * 256;
        vals[k] = (n < NSPK) ? row[n] : -1e30f;
        lmax = fmaxf(lmax, vals[k]);
    }
    #pragma unroll
    for (int m = 1; m < 64; m <<= 1) lmax = fmaxf(lmax, __shfl_xor(lmax, m, 64));
    int wave = tid >> 6;
    if ((tid & 63) == 0) red[wave] = lmax;
    __syncthreads();
    float gmax = fmaxf(fmaxf(red[0], red[1]), fmaxf(red[2], red[3]));
    float lsum = 0.f;
    #pragma unroll
    for (int k = 0; k < 5; k++) {
        int n = tid + k * 256;
        if (n < NSPK) lsum += __expf(vals[k] - gmax);
    }
    #pragma unroll
    for (int m = 1; m < 64; m <<= 1) lsum += __shfl_xor(lsum, m, 64);
    if ((tid & 63) == 0) red[4 + wave] = lsum;
    __syncthreads();
    float lse = logf(red[4] + red[5] + red[6] + red[7]) + gmax;
    #pragma unroll
    for (int k = 0; k < 5; k++) {
        int n = tid + k * 256;
        if (n < NSPK) row[n] = vals[k] - lse;
    }
}

extern "C" void kernel_launch(void* const* d_in, const int* in_sizes, int n_in,
                              void* d_out, int out_size, void* d_ws, size_t ws_size,
                              hipStream_t stream) {
    const float* x     = (const float*)d_in[0];
    const float* w_ih0 = (const float*)d_in[1];
    const float* w_hh0 = (const float*)d_in[2];
    const float* b_ih0 = (const float*)d_in[3];
    const float* b_hh0 = (const float*)d_in[4];
    const float* w_ih1 = (const float*)d_in[5];
    const float* w_hh1 = (const float*)d_in[6];
    const float* b_ih1 = (const float*)d_in[7];
    const float* b_hh1 = (const float*)d_in[8];
    const float* w_ih2 = (const float*)d_in[9];
    const float* w_hh2 = (const float*)d_in[10];
    const float* b_ih2 = (const float*)d_in[11];
    const float* b_hh2 = (const float*)d_in[12];
    const float* w_lin = (const float*)d_in[13];
    const float* b_lin = (const float*)d_in[14];

    unsigned long long* hbuf = (unsigned long long*)d_ws;
    float* h2f = (float*)((char*)d_ws + H2F_OFF_BYTES);
    float* out = (float*)d_out;

    k0_init<<<1, 1024, 0, stream>>>(hbuf);
    k2_lstm<<<NBLOCKS, K2_THREADS, 0, stream>>>(
        x, w_ih0, w_hh0, b_ih0, b_hh0,
        w_ih1, w_hh1, b_ih1, b_hh1,
        w_ih2, w_hh2, b_ih2, b_hh2,
        hbuf, h2f);
    k3_logits<<<dim3(16, 20), 256, 0, stream>>>(h2f, w_lin, b_lin, out);
    k4_logsoftmax<<<T_STEPS, 256, 0, stream>>>(out);
}

// Round 12
// 1618.010 us; speedup vs baseline: 1.1374x; 1.1374x over previous
//
#include <hip/hip_runtime.h>

#define HID 256
#define T_STEPS 1024
#define F_IN 40
#define NSPK 1251
#define NCHUNK 8            // workgroups per layer
#define NBLOCKS 64          // 8 XCD slots x 8 chunks; blocks with (bid&7)>=3 exit
#define K2_THREADS 512

// workspace layout:
//   tagged h words: u64 hbuf[3][1025][256]   (tag = time index, low 32 = float bits)
//   plain float h2f[1024][256] for the logits GEMM
#define HBUF_WORDS (3 * 1025 * 256)
#define H2F_OFF_BYTES ((size_t)HBUF_WORDS * 8)

__device__ __forceinline__ float fast_sig(float v) {
    return __builtin_amdgcn_rcpf(1.f + __expf(-v));
}
__device__ __forceinline__ float fast_tanh(float v) {
    return 2.f * __builtin_amdgcn_rcpf(1.f + __expf(-2.f * v)) - 1.f;
}

// Agent-scope pipelined tagged-word poll. Depth 4 is the measured optimum
// (R2: dependent poll worse; R10: depth 6 worse -- extra same-address samples
// queue at the coherence point). Word is write-once so any matching sample is valid.
__device__ __forceinline__ float poll_word(const unsigned long long* p, unsigned want) {
    unsigned long long v0 = __hip_atomic_load(p, __ATOMIC_RELAXED, __HIP_MEMORY_SCOPE_AGENT);
    if ((unsigned)(v0 >> 32) == want) return __uint_as_float((unsigned)v0);  // steady-state hit
    unsigned long long v1 = __hip_atomic_load(p, __ATOMIC_RELAXED, __HIP_MEMORY_SCOPE_AGENT);
    unsigned long long v2 = __hip_atomic_load(p, __ATOMIC_RELAXED, __HIP_MEMORY_SCOPE_AGENT);
    unsigned long long v3 = __hip_atomic_load(p, __ATOMIC_RELAXED, __HIP_MEMORY_SCOPE_AGENT);
    for (;;) {
        if ((unsigned)(v0 >> 32) == want) return __uint_as_float((unsigned)v0);
        v0 = v1; v1 = v2; v2 = v3;
        v3 = __hip_atomic_load(p, __ATOMIC_RELAXED, __HIP_MEMORY_SCOPE_AGENT);
    }
}

// ---------------- K0: init h[l][0][:] = (tag 0 | 0.0f) ----------------
__global__ void k0_init(unsigned long long* __restrict__ hbuf) {
    int tid = threadIdx.x;
    if (tid < 3 * HID) {
        int l = tid / HID, k = tid % HID;
        hbuf[(size_t)(l * 1025 + 0) * HID + k] = 0ull;   // tag 0, value 0.0f
    }
}

// ---------------- K2: pipelined 3-layer LSTM, tagged-word sync ----------------
// R4 structure -- best measured configuration (k2 ~1540us, total 1631us).
// Eight sync-side variants (R5-R11) all regressed; see session notes. The step
// period is ~3600 cy: ~800 cy work + ~2800 cy store->MALL->load visibility floor.
// Block mapping: bid = g*8 + layer so all 8 chunks of a layer share one XCD under
// round-robin dispatch (cuts HBM/MALL traffic ~3x; latency unaffected -- R3).
// Thread mapping (block = one layer-chunk of 32 h):
//   seg = tid >> 5 (0..15): 32-wide k-segment of [input(256); own-h(256)]
//   wave w owns segs {2w,2w+1} = k-range [64w,64w+64) -- gather/bounce/dot are
//   wave-PRIVATE (no cross-wave buf sharing -> no barrier around the bounce).
// Per step per wave: poll 1 word/lane -> ds_write_b32 -> 8x broadcast ds_read_b128
// + 128 FMA (R=4: 4 gate rows/thread) -> shfl_xor(32) seg-fold -> one packed
// ds_write_b128 into parity-double-buffered gatebuf -> ONE s_barrier -> wave 0
// lanes 0..31 sum 8 partials, nonlinearity, aggregated coalesced 32-lane tagged
// publish (aggregation matters: consumers detect all 32 words in one poll quantum).
__global__ __launch_bounds__(K2_THREADS) void k2_lstm(
    const float* __restrict__ x,
    const float* __restrict__ w_ih0, const float* __restrict__ w_hh0,
    const float* __restrict__ b_ih0, const float* __restrict__ b_hh0,
    const float* __restrict__ w_ih1, const float* __restrict__ w_hh1,
    const float* __restrict__ b_ih1, const float* __restrict__ b_hh1,
    const float* __restrict__ w_ih2, const float* __restrict__ w_hh2,
    const float* __restrict__ b_ih2, const float* __restrict__ b_hh2,
    unsigned long long* __restrict__ hbuf, float* __restrict__ h2f)
{
    const int bid = blockIdx.x;
    const int xslot = bid & 7;           // XCD slot under round-robin dispatch
    if (xslot >= 3) return;              // only 3 layers; 40 of 64 blocks idle-exit
    const int layer = xslot;             // all 8 chunks of a layer share an XCD
    const int g     = bid >> 3;          // chunk of 32 h-indices
    const int tid   = threadIdx.x;
    const int seg = tid >> 5;            // k-segment 0..15 (32 wide each)
    const int j   = tid & 31;            // local h-index
    const int wv  = tid >> 6;            // wave 0..7
    const int jg  = g * 32 + j;          // global h-index within layer

    const float* wih = (layer == 0) ? w_ih0 : (layer == 1) ? w_ih1 : w_ih2;
    const float* whh = (layer == 0) ? w_hh0 : (layer == 1) ? w_hh1 : w_hh2;
    const float* bih = (layer == 0) ? b_ih0 : (layer == 1) ? b_ih1 : b_ih2;
    const float* bhh = (layer == 0) ? b_hh0 : (layer == 1) ? b_hh1 : b_hh2;

    // layer 0: k in [64,256) is all-zero input -> waves 1..3 have nothing to do
    const bool dead = (layer == 0) && (seg >= 2) && (seg < 8);

    __shared__ float  buf[512];          // bounce buffer; wave-private 64-word regions
    __shared__ float4 gatebuf[2][8][32]; // [t-parity][wave][j] = 4 gate partials

    // ---- weights: w[q][i] = W_row(q*256+jg)[ seg*32 + i ]  (contiguous) ----
    float w[4][32];
    float bb[4];
    if (!dead) {
        #pragma unroll
        for (int q = 0; q < 4; q++) {
            const int r = q * 256 + jg;
            bb[q] = bih[r] + bhh[r];
            const int k0 = seg * 32;
            if (k0 >= 256) {
                const float4* src = (const float4*)(whh + (size_t)r * HID + (k0 - 256));
                #pragma unroll
                for (int i4 = 0; i4 < 8; i4++) {
                    float4 v = src[i4];
                    w[q][i4*4+0] = v.x; w[q][i4*4+1] = v.y;
                    w[q][i4*4+2] = v.z; w[q][i4*4+3] = v.w;
                }
            } else if (layer > 0) {
                const float4* src = (const float4*)(wih + (size_t)r * HID + k0);
                #pragma unroll
                for (int i4 = 0; i4 < 8; i4++) {
                    float4 v = src[i4];
                    w[q][i4*4+0] = v.x; w[q][i4*4+1] = v.y;
                    w[q][i4*4+2] = v.z; w[q][i4*4+3] = v.w;
                }
            } else {
                // layer 0, seg 0/1: 40-wide x projection, zero-padded
                #pragma unroll
                for (int i = 0; i < 32; i++) {
                    int k = k0 + i;
                    w[q][i] = (k < F_IN) ? w_ih0[r * F_IN + k] : 0.f;
                }
            }
        }
    } else {
        #pragma unroll
        for (int q = 0; q < 4; q++) {
            bb[q] = 0.f;
            #pragma unroll
            for (int i = 0; i < 32; i++) w[q][i] = 0.f;
        }
    }

    for (int i = tid; i < 512; i += K2_THREADS) buf[i] = 0.f;
    __syncthreads();

    const float* x63 = x + 63 * T_STEPS * F_IN;
    const unsigned long long* h_prev = hbuf + (size_t)(layer - 1) * 1025 * HID; // layer>0 only
    unsigned long long* h_own        = hbuf + (size_t)layer * 1025 * HID;

    float px = 0.f;                      // layer-0 x prefetch (lanes tid<40)
    if (layer == 0 && tid < F_IN) px = x63[tid];

    float c_state = 0.f;                 // valid on tid<32 (update lanes, wave 0)

    for (int t = 0; t < T_STEPS; t++) {
        // ---- gather: each lane polls/loads word tid of the 512-wide input vec ----
        if (!dead) {
            if (tid < 256) {
                if (layer > 0) {
                    // prev-layer h[t+1]: published ~one period early (chain has slack)
                    buf[tid] = poll_word(h_prev + (size_t)(t + 1) * HID + tid,
                                         (unsigned)(t + 1));
                } else if (tid < F_IN) {
                    buf[tid] = px;       // prefetched x[t]; issue load of x[t+1]
                    if (t + 1 < T_STEPS) px = x63[(t + 1) * F_IN + tid];
                }
                // layer 0, 40 <= tid < 256: stays 0 (weights there are 0 too)
            } else {
                // own-layer h[t] incl. own chunk -- the critical-cycle poll
                buf[tid] = poll_word(h_own + (size_t)t * HID + (tid - 256),
                                     (unsigned)t);
            }
        }

        // ---- wave-private bounce: ds_write above, broadcast ds_read_b128 below ----
        float4 part = make_float4(0.f, 0.f, 0.f, 0.f);
        if (!dead) {
            __asm__ volatile("s_waitcnt lgkmcnt(0)" ::: "memory");
            const float4* b4 = (const float4*)buf + seg * 8;
            float a0 = 0.f, a1 = 0.f, a2 = 0.f, a3 = 0.f;
            #pragma unroll
            for (int i4 = 0; i4 < 8; i4++) {
                float4 f = b4[i4];
                a0 += w[0][i4*4+0]*f.x + w[0][i4*4+1]*f.y + w[0][i4*4+2]*f.z + w[0][i4*4+3]*f.w;
                a1 += w[1][i4*4+0]*f.x + w[1][i4*4+1]*f.y + w[1][i4*4+2]*f.z + w[1][i4*4+3]*f.w;
                a2 += w[2][i4*4+0]*f.x + w[2][i4*4+1]*f.y + w[2][i4*4+2]*f.z + w[2][i4*4+3]*f.w;
                a3 += w[3][i4*4+0]*f.x + w[3][i4*4+1]*f.y + w[3][i4*4+2]*f.z + w[3][i4*4+3]*f.w;
            }
            // fold the wave's two segs (lanes L and L^32 share j)
            a0 += __shfl_xor(a0, 32, 64);
            a1 += __shfl_xor(a1, 32, 64);
            a2 += __shfl_xor(a2, 32, 64);
            a3 += __shfl_xor(a3, 32, 64);
            part = make_float4(a0, a1, a2, a3);
        }
        // one packed b128 write per wave (lanes 0..31): full-rate, conflict-free
        if ((tid & 32) == 0) gatebuf[t & 1][wv][j] = part;
        __syncthreads();                 // the ONLY barrier per step

        // ---- update + immediate aggregated publish (wave 0, lanes 0..31) ----
        if (tid < 32) {
            float4 s = gatebuf[t & 1][0][tid];
            #pragma unroll
            for (int w8 = 1; w8 < 8; w8++) {
                float4 v = gatebuf[t & 1][w8][tid];
                s.x += v.x; s.y += v.y; s.z += v.z; s.w += v.w;
            }
            float si = fast_sig(s.x + bb[0]);
            float sf = fast_sig(s.y + bb[1]);
            float gg = fast_tanh(s.z + bb[2]);
            float so = fast_sig(s.w + bb[3]);
            c_state = sf * c_state + si * gg;
            float hv = so * fast_tanh(c_state);
            unsigned long long word =
                ((unsigned long long)(unsigned)(t + 1) << 32) | (unsigned long long)__float_as_uint(hv);
            __hip_atomic_store(h_own + (size_t)(t + 1) * HID + g * 32 + tid, word,
                               __ATOMIC_RELAXED, __HIP_MEMORY_SCOPE_AGENT);
            if (layer == 2) h2f[(size_t)t * HID + g * 32 + tid] = hv;
        }
        // gatebuf WAR across steps is safe: writers of parity p at step t+2 have
        // passed barrier(t+1), which wave 0 reaches only after reading parity p at
        // step t. No second barrier needed; tag rides in the publish word.
    }
}

// ---------------- K3: logits = h2 @ w_lin^T + b_lin (tiled fp32 GEMM) ----------------
#define BM 64
#define BN 64
#define BK 32
__global__ __launch_bounds__(256) void k3_logits(
    const float* __restrict__ A, const float* __restrict__ w_lin,
    const float* __restrict__ b_lin, float* __restrict__ out)
{
    int m0 = blockIdx.x * BM;
    int n0 = blockIdx.y * BN;
    int tid = threadIdx.x;
    __shared__ float As[BM][BK + 1];
    __shared__ float Bs[BN][BK + 1];
    float accv[4][4] = {};
    int tx = tid % 16, ty = tid / 16;

    for (int k0 = 0; k0 < HID; k0 += BK) {
        int row = tid / 4;
        int kq  = (tid % 4) * 8;
        {
            const float4* src = (const float4*)(A + (m0 + row) * HID + k0 + kq);
            float4 v0 = src[0], v1 = src[1];
            As[row][kq + 0] = v0.x; As[row][kq + 1] = v0.y; As[row][kq + 2] = v0.z; As[row][kq + 3] = v0.w;
            As[row][kq + 4] = v1.x; As[row][kq + 5] = v1.y; As[row][kq + 6] = v1.z; As[row][kq + 7] = v1.w;
        }
        {
            int n = n0 + row;
            float4 v0 = make_float4(0.f, 0.f, 0.f, 0.f), v1 = v0;
            if (n < NSPK) {
                const float4* src = (const float4*)(w_lin + n * HID + k0 + kq);
                v0 = src[0]; v1 = src[1];
            }
            Bs[row][kq + 0] = v0.x; Bs[row][kq + 1] = v0.y; Bs[row][kq + 2] = v0.z; Bs[row][kq + 3] = v0.w;
            Bs[row][kq + 4] = v1.x; Bs[row][kq + 5] = v1.y; Bs[row][kq + 6] = v1.z; Bs[row][kq + 7] = v1.w;
        }
        __syncthreads();
        #pragma unroll
        for (int kk = 0; kk < BK; kk++) {
            float a0 = As[ty * 4 + 0][kk], a1 = As[ty * 4 + 1][kk];
            float a2 = As[ty * 4 + 2][kk], a3 = As[ty * 4 + 3][kk];
            float b0 = Bs[tx * 4 + 0][kk], b1 = Bs[tx * 4 + 1][kk];
            float b2 = Bs[tx * 4 + 2][kk], b3 = Bs[tx * 4 + 3][kk];
            accv[0][0] += a0 * b0; accv[0][1] += a0 * b1; accv[0][2] += a0 * b2; accv[0][3] += a0 * b3;
            accv[1][0] += a1 * b0; accv[1][1] += a1 * b1; accv[1][2] += a1 * b2; accv[1][3] += a1 * b3;
            accv[2][0] += a2 * b0; accv[2][1] += a2 * b1; accv[2][2] += a2 * b2; accv[2][3] += a2 * b3;
            accv[3][0] += a3 * b0; accv[3][1] += a3 * b1; accv[3][2] += a3 * b2; accv[3][3] += a3 * b3;
        }
        __syncthreads();
    }
    #pragma unroll
    for (int i = 0; i < 4; i++) {
        int m = m0 + ty * 4 + i;
        #pragma unroll
        for (int j = 0; j < 4; j++) {
            int n = n0 + tx * 4 + j;
            if (n < NSPK) out[(size_t)m * NSPK + n] = accv[i][j] + b_lin[n];
        }
    }
}

// ---------------- K4: in-place row-wise log_softmax over NSPK ----------------
__global__ __launch_bounds__(256) void k4_logsoftmax(float* __restrict__ out)
{
    int t = blockIdx.x;
    float* row = out + (size_t)t * NSPK;
    int tid = threadIdx.x;
    __shared__ float red[8];
    float vals[5];
    float lmax = -1e30f;
    #pragma unroll
    for (int k = 0; k < 5; k++) {
        int n = tid + k * 256;
        vals[k] = (n < NSPK) ? row[n] : -1e30f;
        lmax = fmaxf(lmax, vals[k]);
    }
    #pragma unroll
    for (int m = 1; m < 64; m <<= 1) lmax = fmaxf(lmax, __shfl_xor(lmax, m, 64));
    int wave = tid >> 6;
    if ((tid & 63) == 0) red[wave] = lmax;
    __syncthreads();
    float gmax = fmaxf(fmaxf(red[0], red[1]), fmaxf(red[2], red[3]));
    float lsum = 0.f;
    #pragma unroll
    for (int k = 0; k < 5; k++) {
        int n = tid + k * 256;
        if (n < NSPK) lsum += __expf(vals[k] - gmax);
    }
    #pragma unroll
    for (int m = 1; m < 64; m <<= 1) lsum += __shfl_xor(lsum, m, 64);
    if ((tid & 63) == 0) red[4 + wave] = lsum;
    __syncthreads();
    float lse = logf(red[4] + red[5] + red[6] + red[7]) + gmax;
    #pragma unroll
    for (int k = 0; k < 5; k++) {
        int n = tid + k * 256;
        if (n < NSPK) row[n] = vals[k] - lse;
    }
}

extern "C" void kernel_launch(void* const* d_in, const int* in_sizes, int n_in,
                              void* d_out, int out_size, void* d_ws, size_t ws_size,
                              hipStream_t stream) {
    const float* x     = (const float*)d_in[0];
    const float* w_ih0 = (const float*)d_in[1];
    const float* w_hh0 = (const float*)d_in[2];
    const float* b_ih0 = (const float*)d_in[3];
    const float* b_hh0 = (const float*)d_in[4];
    const float* w_ih1 = (const float*)d_in[5];
    const float* w_hh1 = (const float*)d_in[6];
    const float* b_ih1 = (const float*)d_in[7];
    const float* b_hh1 = (const float*)d_in[8];
    const float* w_ih2 = (const float*)d_in[9];
    const float* w_hh2 = (const float*)d_in[10];
    const float* b_ih2 = (const float*)d_in[11];
    const float* b_hh2 = (const float*)d_in[12];
    const float* w_lin = (const float*)d_in[13];
    const float* b_lin = (const float*)d_in[14];

    unsigned long long* hbuf = (unsigned long long*)d_ws;
    float* h2f = (float*)((char*)d_ws + H2F_OFF_BYTES);
    float* out = (float*)d_out;

    k0_init<<<1, 1024, 0, stream>>>(hbuf);
    k2_lstm<<<NBLOCKS, K2_THREADS, 0, stream>>>(
        x, w_ih0, w_hh0, b_ih0, b_hh0,
        w_ih1, w_hh1, b_ih1, b_hh1,
        w_ih2, w_hh2, b_ih2, b_hh2,
        hbuf, h2f);
    k3_logits<<<dim3(16, 20), 256, 0, stream>>>(h2f, w_lin, b_lin, out);
    k4_logsoftmax<<<T_STEPS, 256, 0, stream>>>(out);
}